// Round 4
// baseline (517.443 us; speedup 1.0000x reference)
//
#include <hip/hip_runtime.h>
#include <hip/hip_bf16.h>

// ScannedLSTM: B=512, T=512, F=64, H=64 (4H=256)
// R4: reset-segment decomposition.
//   detect   : classify resets dtype (int32 / uint8 / float32 bit patterns)
//   seg_build: per row, segments = maximal reset-free runs; pack (b,ts,len)
//   zgemm3   : Z[bt][p]=bias+x@Wi (bf16), permuted p=j*4+gate so recur reads
//              one coalesced uint2 per lane per step. MFMA 16x16x32_bf16.
//   lstm_recur3: wave-per-segment, 4 segment slots in flight per wave (ILP),
//              lane j owns h-col j (all 4 gates, 256 Wh regs), h broadcast via
//              wave-private LDS, no barriers, no resets (segments reset-free).

typedef __attribute__((ext_vector_type(8))) short short8;
typedef __attribute__((ext_vector_type(4))) float f32x4;

#define NB 512
#define NT 512
#define NF 64
#define NH 64
#define NG 256
#define TCHUNK 32
#define NWAVES 2048   // recur: 512 blocks x 4 waves, grid-stride queue

__device__ __forceinline__ float rcp_fast(float x) { return __builtin_amdgcn_rcpf(x); }
__device__ __forceinline__ float sig_fast(float x) { return rcp_fast(1.0f + __expf(-x)); }
__device__ __forceinline__ float tanh_fast(float x) {
    return 1.0f - 2.0f * rcp_fast(1.0f + __expf(2.0f * x));
}
__device__ __forceinline__ unsigned pkbf(float a, float b) {  // -> v_cvt_pk_bf16_f32
    __hip_bfloat162 h = __float22bfloat162_rn(make_float2(a, b));
    unsigned u; __builtin_memcpy(&u, &h, 4); return u;
}
__device__ __forceinline__ unsigned short f2bf(float x) {
    unsigned u = __float_as_uint(x);
    return (unsigned short)((u + 0x7FFFu + ((u >> 16) & 1u)) >> 16);
}

// ---- resets dtype detector --------------------------------------------------
__global__ void detect_resets_dtype(const unsigned int* __restrict__ r, int n,
                                    int* __restrict__ flag) {
    int bits = 0;
    for (int i = blockIdx.x * blockDim.x + threadIdx.x; i < n;
         i += gridDim.x * blockDim.x) {
        unsigned v = r[i];
        if (v == 0x3F800000u) bits |= 2;
        else if (v != 0u && v != 1u) bits |= 4;
    }
    if (bits) atomicOr(flag, bits);
}
__device__ __forceinline__ int decode_mode(const int* flag) {
    int fl = *flag;
    if ((fl & 2) && !(fl & 4)) return 2;   // float32
    if (fl & 4) return 1;                  // uint8
    return 0;                              // int32
}
__device__ __forceinline__ int load_rst(const void* resets, int mode, long idx) {
    if (mode == 1) return ((const unsigned char*)resets)[idx] != 0;
    if (mode == 2) return ((const float*)resets)[idx] != 0.0f;
    return ((const int*)resets)[idx] != 0;
}

// ---- segment list build: one wave per batch row -----------------------------
// pack = (b<<19) | (ts<<10) | len   (b:9b, ts:9b, len:10b up to 512)
__global__ __launch_bounds__(64)
void seg_build(const void* __restrict__ resets, const int* __restrict__ flag,
               unsigned* __restrict__ list, int* __restrict__ cnt) {
    const int b = blockIdx.x;
    const int tid = threadIdx.x;
    const int mode = decode_mode(flag);
    __shared__ unsigned char r[NT];
#pragma unroll
    for (int i = 0; i < NT / 64; ++i)
        r[tid + 64 * i] = (unsigned char)load_rst(resets, mode, (long)b * NT + tid + 64 * i);
    __syncthreads();
#pragma unroll
    for (int i = 0; i < NT / 64; ++i) {
        const int t = tid + 64 * i;
        if (t == 0 || r[t]) {
            int e = t + 1;
            while (e < NT && !r[e]) ++e;
            const int idx = atomicAdd(cnt, 1);
            list[idx] = ((unsigned)b << 19) | ((unsigned)t << 10) | (unsigned)(e - t);
        }
    }
}

// ---- Phase 1: Z(bf16, permuted p=j*4+g) = bias + ins @ Wi -------------------
// A[m=p][k] = Wi[k][(p&3)*64+(p>>2)]; B[k][n=bt] = ins[bt][k]  (R2-verified)
// D lane map: col(bt) = lane&15, row(p) = (lane>>4)*4 + reg
__global__ __launch_bounds__(256, 2)
void zgemm3(const float* __restrict__ ins, const float* __restrict__ Wi,
            const float* __restrict__ bias, unsigned short* __restrict__ Z) {
    const int tid = threadIdx.x;
    const int lane = tid & 63;
    const int w = tid >> 6;
    const int l15 = lane & 15, l4 = lane >> 4;
    const long bt0 = (long)blockIdx.x * 64;
    const int pbase = w << 6;

    __shared__ __align__(16) unsigned short xs[64][72];  // bf16, 144B rows

    {   // stage 64x64 f32 -> bf16 LDS, coalesced, cvt_pk conversions
        const float4* src = (const float4*)(ins + bt0 * NF);
#pragma unroll
        for (int i = 0; i < 4; ++i) {
            const int q = tid + 256 * i;
            const int row = q >> 4, c4 = (q & 15) << 2;
            const float4 v = src[q];
            *(uint2*)&xs[row][c4] = make_uint2(pkbf(v.x, v.y), pkbf(v.z, v.w));
        }
    }

    short8 afr[4][2];
    f32x4 binit[4];
#pragma unroll
    for (int pt = 0; pt < 4; ++pt) {
        const int prow = pbase + pt * 16 + l15;
        const int n = (prow & 3) * 64 + (prow >> 2);
#pragma unroll
        for (int kc = 0; kc < 2; ++kc) {
            union { unsigned u[4]; short8 s; } cv;
#pragma unroll
            for (int e2 = 0; e2 < 4; ++e2) {
                const int k = kc * 32 + l4 * 8 + e2 * 2;
                cv.u[e2] = pkbf(Wi[k * NG + n], Wi[(k + 1) * NG + n]);
            }
            afr[pt][kc] = cv.s;
        }
        f32x4 bi;
#pragma unroll
        for (int r = 0; r < 4; ++r) {
            const int pr = pbase + pt * 16 + l4 * 4 + r;
            bi[r] = bias[(pr & 3) * 64 + (pr >> 2)];
        }
        binit[pt] = bi;
    }
    __syncthreads();

#pragma unroll
    for (int tt = 0; tt < 4; ++tt) {
        short8 bfr[2];
#pragma unroll
        for (int kc = 0; kc < 2; ++kc)
            bfr[kc] = *(const short8*)&xs[tt * 16 + l15][kc * 32 + l4 * 8];
        const long bt = bt0 + tt * 16 + l15;
#pragma unroll
        for (int pt = 0; pt < 4; ++pt) {
            f32x4 acc = binit[pt];
            acc = __builtin_amdgcn_mfma_f32_16x16x32_bf16(afr[pt][0], bfr[0], acc, 0, 0, 0);
            acc = __builtin_amdgcn_mfma_f32_16x16x32_bf16(afr[pt][1], bfr[1], acc, 0, 0, 0);
            const int p0 = pbase + pt * 16 + l4 * 4;
            *(uint2*)&Z[bt * NG + p0] =
                make_uint2(pkbf(acc[0], acc[1]), pkbf(acc[2], acc[3]));
        }
    }
}

// ---- Phase 2: segmented recurrence, 4 slots/wave, no barriers ---------------
__global__ __launch_bounds__(256, 1)
void lstm_recur3(const uint2* __restrict__ Z2, const float* __restrict__ Wh,
                 float* __restrict__ out, const unsigned* __restrict__ list,
                 const int* __restrict__ cnt) {
    const int tid = threadIdx.x;
    const int j = tid & 63;
    const int wv = __builtin_amdgcn_readfirstlane(tid >> 6);
    const int wid = __builtin_amdgcn_readfirstlane((int)blockIdx.x * 4 + (tid >> 6));
    const int nseg = __builtin_amdgcn_readfirstlane(*cnt);

    // 256 Wh regs: lane j holds Wh[:, g*64+j] for all 4 gates
    float whi[NF], whf[NF], whg[NF], who[NF];
#pragma unroll
    for (int k = 0; k < NF; ++k) {
        whi[k] = Wh[k * NG + j];
        whf[k] = Wh[k * NG + NH + j];
        whg[k] = Wh[k * NG + 2 * NH + j];
        who[k] = Wh[k * NG + 3 * NH + j];
    }

    __shared__ __align__(16) float hls[4][4][NH];  // [wave][slot][col], 4 KB

    int qi = wid;
    long ob0, ob1, ob2, ob3;            // out base (=(b*NT+t)*64), advances by 64
    int rem0 = 0, rem1 = 0, rem2 = 0, rem3 = 0;
    int act0 = 0, act1 = 0, act2 = 0, act3 = 0;
    int fr0 = 0, fr1 = 0, fr2 = 0, fr3 = 0;
    float c0 = 0, c1 = 0, c2 = 0, c3 = 0;
    uint2 zz0, zz1, zz2, zz3;

#define POP(S) do {                                                            \
        if (qi < nseg) {                                                       \
            const unsigned sg = __builtin_amdgcn_readfirstlane(list[qi]);      \
            qi += NWAVES;                                                      \
            const int sb = (int)(sg >> 19);                                    \
            const int st = (int)((sg >> 10) & 511u);                           \
            rem##S = (int)(sg & 1023u);                                        \
            ob##S = ((long)sb * NT + st) * 64;                                 \
            zz##S = Z2[ob##S + j];                                             \
            act##S = 1; fr##S = 1; c##S = 0.0f;                                \
        } else { act##S = 0; }                                                 \
    } while (0)

#define STEP(S) do {                                                           \
        float si = __uint_as_float(zz##S.x << 16);                             \
        float sf = __uint_as_float(zz##S.x & 0xFFFF0000u);                     \
        float sg_ = __uint_as_float(zz##S.y << 16);                            \
        float so = __uint_as_float(zz##S.y & 0xFFFF0000u);                     \
        if (!fr##S) {                                                          \
            const f32x4* hp = (const f32x4*)&hls[wv][S][0];                    \
            _Pragma("unroll")                                                  \
            for (int q = 0; q < 16; ++q) {                                     \
                const f32x4 hv = hp[q];                                        \
                si = fmaf(hv[0], whi[4 * q + 0], si);                          \
                si = fmaf(hv[1], whi[4 * q + 1], si);                          \
                si = fmaf(hv[2], whi[4 * q + 2], si);                          \
                si = fmaf(hv[3], whi[4 * q + 3], si);                          \
                sf = fmaf(hv[0], whf[4 * q + 0], sf);                          \
                sf = fmaf(hv[1], whf[4 * q + 1], sf);                          \
                sf = fmaf(hv[2], whf[4 * q + 2], sf);                          \
                sf = fmaf(hv[3], whf[4 * q + 3], sf);                          \
                sg_ = fmaf(hv[0], whg[4 * q + 0], sg_);                        \
                sg_ = fmaf(hv[1], whg[4 * q + 1], sg_);                        \
                sg_ = fmaf(hv[2], whg[4 * q + 2], sg_);                        \
                sg_ = fmaf(hv[3], whg[4 * q + 3], sg_);                        \
                so = fmaf(hv[0], who[4 * q + 0], so);                          \
                so = fmaf(hv[1], who[4 * q + 1], so);                          \
                so = fmaf(hv[2], who[4 * q + 2], so);                          \
                so = fmaf(hv[3], who[4 * q + 3], so);                          \
            }                                                                  \
        }                                                                      \
        const float ig = sig_fast(si);                                         \
        const float fg = sig_fast(sf);                                         \
        const float gg = tanh_fast(sg_);                                       \
        const float og = sig_fast(so);                                         \
        c##S = fr##S ? (ig * gg) : fmaf(fg, c##S, ig * gg);                    \
        const float hh = og * tanh_fast(c##S);                                 \
        out[ob##S + j] = hh;                                                   \
        hls[wv][S][j] = hh;                                                    \
        ob##S += 64;                                                           \
        if (--rem##S > 0) zz##S = Z2[ob##S + j]; else act##S = 0;              \
        fr##S = 0;                                                             \
    } while (0)

    for (;;) {
        if (!act0) POP(0);
        if (!act1) POP(1);
        if (!act2) POP(2);
        if (!act3) POP(3);
        if (!(act0 | act1 | act2 | act3)) break;
        if (act0) STEP(0);
        if (act1) STEP(1);
        if (act2) STEP(2);
        if (act3) STEP(3);
    }
#undef POP
#undef STEP
}

// ---- Fallback (R1 kernel, known-good) ---------------------------------------
__global__ __launch_bounds__(256, 2)
void lstm_scan_kernel(const float* __restrict__ ins, const void* __restrict__ resets,
                      const float* __restrict__ Wi, const float* __restrict__ Wh,
                      const float* __restrict__ bias, float* __restrict__ out,
                      const int* __restrict__ flag) {
    const int b = blockIdx.x;
    const int j = threadIdx.x;
    int mode = flag ? decode_mode(flag) : 0;

    float wi[NF], wh[NF];
#pragma unroll
    for (int k = 0; k < NF; ++k) {
        wi[k] = Wi[k * NG + j];
        wh[k] = Wh[k * NG + j];
    }
    const float bj = bias[j];

    __shared__ __align__(16) float xs[TCHUNK][NF];
    __shared__ int rs[TCHUNK];
    __shared__ __align__(16) float hbuf[2][NH];
    __shared__ float zbuf[NG];

    float c = 0.0f;
    if (j < NH) { hbuf[0][j] = 0.0f; hbuf[1][j] = 0.0f; }
    __syncthreads();

    int cur = 0;
    for (int t0 = 0; t0 < NT; t0 += TCHUNK) {
        {
            const float4* src = (const float4*)(ins + ((size_t)b * NT + t0) * NF);
            float4* dst = (float4*)&xs[0][0];
            dst[j] = src[j];
            dst[j + 256] = src[j + 256];
            if (j < TCHUNK) rs[j] = load_rst(resets, mode, (long)b * NT + t0 + j);
        }
        __syncthreads();

        for (int tt = 0; tt < TCHUNK; ++tt) {
            const int t = t0 + tt;
            const int rst = rs[tt];
            float accx = bj, acch = 0.0f;
            const float4* xv4 = (const float4*)&xs[tt][0];
#pragma unroll
            for (int k4 = 0; k4 < NF / 4; ++k4) {
                float4 xv = xv4[k4];
                accx = fmaf(xv.x, wi[4 * k4 + 0], accx);
                accx = fmaf(xv.y, wi[4 * k4 + 1], accx);
                accx = fmaf(xv.z, wi[4 * k4 + 2], accx);
                accx = fmaf(xv.w, wi[4 * k4 + 3], accx);
            }
            if (!rst) {
                const float4* hv4 = (const float4*)&hbuf[cur][0];
#pragma unroll
                for (int k4 = 0; k4 < NF / 4; ++k4) {
                    float4 hv = hv4[k4];
                    acch = fmaf(hv.x, wh[4 * k4 + 0], acch);
                    acch = fmaf(hv.y, wh[4 * k4 + 1], acch);
                    acch = fmaf(hv.z, wh[4 * k4 + 2], acch);
                    acch = fmaf(hv.w, wh[4 * k4 + 3], acch);
                }
            }
            zbuf[j] = accx + acch;
            __syncthreads();
            if (j < NH) {
                float zi = zbuf[j], zf = zbuf[j + NH], zg = zbuf[j + 2 * NH], zo = zbuf[j + 3 * NH];
                float ig = sig_fast(zi), fg = sig_fast(zf), gg = tanh_fast(zg), og = sig_fast(zo);
                float cc = rst ? 0.0f : c;
                cc = fg * cc + ig * gg;
                c = cc;
                float hh = og * tanh_fast(cc);
                hbuf[cur ^ 1][j] = hh;
                out[((size_t)b * NT + t) * NH + j] = hh;
            }
            __syncthreads();
            cur ^= 1;
        }
    }
}

extern "C" void kernel_launch(void* const* d_in, const int* in_sizes, int n_in,
                              void* d_out, int out_size, void* d_ws, size_t ws_size,
                              hipStream_t stream) {
    const float* ins    = (const float*)d_in[0];
    const void*  resets = d_in[1];
    const float* Wi     = (const float*)d_in[2];
    const float* Wh     = (const float*)d_in[3];
    const float* bias   = (const float*)d_in[4];
    float* out = (float*)d_out;

    const int nBT = NB * NT;
    const size_t ZBF16   = (size_t)nBT * NG * 2;          // 134 MB
    const size_t METAOFF = ZBF16;                          // flag(4) + cnt(4)
    const size_t LISTOFF = ZBF16 + 64;
    const size_t NEEDED  = LISTOFF + (size_t)nBT * 4 + 64; // list up to 262144 segs

    if (ws_size >= NEEDED) {
        unsigned short* Z = (unsigned short*)d_ws;
        int* flag = (int*)((char*)d_ws + METAOFF);
        int* cnt  = flag + 1;
        unsigned* list = (unsigned*)((char*)d_ws + LISTOFF);

        hipMemsetAsync(flag, 0, 8, stream);  // flag + cnt
        detect_resets_dtype<<<256, 256, 0, stream>>>((const unsigned int*)resets, nBT, flag);
        seg_build<<<NB, 64, 0, stream>>>(resets, flag, list, cnt);
        zgemm3<<<nBT / 64, 256, 0, stream>>>(ins, Wi, bias, Z);
        lstm_recur3<<<NWAVES / 4, 256, 0, stream>>>((const uint2*)Z, Wh, out, list, cnt);
    } else {
        int* flag = nullptr;
        if (d_ws && ws_size >= sizeof(int)) {
            flag = (int*)d_ws;
            hipMemsetAsync(flag, 0, sizeof(int), stream);
            detect_resets_dtype<<<256, 256, 0, stream>>>((const unsigned int*)resets, nBT, flag);
        }
        lstm_scan_kernel<<<NB, 256, 0, stream>>>(ins, resets, Wi, Wh, bias, out, flag);
    }
}